// Round 15
// baseline (314.112 us; speedup 1.0000x reference)
//
#include <hip/hip_runtime.h>

#define NB 8
#define LSEQ 1024
#define DM 64
#define DFF 256
#define NLAYER 4
#define NROW (NB*LSEQ)
#define LOG2E 1.44269504088896f
#define PAD2  (-1.442695e9f)
#define EXP2(x) __builtin_amdgcn_exp2f(x)

typedef float v2f __attribute__((ext_vector_type(2)));
#define PKFMA(d, a, b) asm("v_pk_fma_f32 %0, %1, %2, %0" : "+v"(d) : "v"(a), "v"(b))

__device__ __forceinline__ float wsum64(float v){
  #pragma unroll
  for (int off = 32; off; off >>= 1) v += __shfl_xor(v, off);
  return v;
}
__device__ __forceinline__ float wmax64(float v){
  #pragma unroll
  for (int off = 32; off; off >>= 1) v = fmaxf(v, __shfl_xor(v, off));
  return v;
}

// ---- nz per batch ----
__global__ void nz_kernel(const int* __restrict__ protok, float* __restrict__ nz){
  __shared__ float sm[16];
  int t = threadIdx.x;
  float v = (protok[blockIdx.x * LSEQ + t] != 0) ? 1.f : 0.f;
  v = wsum64(v);
  if ((t & 63) == 0) sm[t >> 6] = v;
  __syncthreads();
  if (t < 16){
    float s = sm[t];
    #pragma unroll
    for (int off = 8; off; off >>= 1) s += __shfl_xor(s, off);
    if (t == 0) nz[blockIdx.x] = s;
  }
}

// ================== FAST PATH ==================

// ---- QKV projection, 2 rows/thread (round-12 proven) ----
__global__ __launch_bounds__(256, 4) void qkv_proj(
    const float* __restrict__ xin, const int* __restrict__ protok,
    const float* __restrict__ Wq, const float* __restrict__ bq,
    const float* __restrict__ Wk, const float* __restrict__ bk,
    const float* __restrict__ Wv, const float* __restrict__ bv,
    float* __restrict__ qb, float* __restrict__ kb, float* __restrict__ vb)
{
  int t = threadIdx.x, rl = t >> 6, c = t & 63;
  int r0 = blockIdx.x * 8;
  int rA = r0 + rl, rB = rA + 4;
  size_t offA = (size_t)rA * DM + c, offB = (size_t)rB * DM + c;
  __shared__ float xs[8][64];
  xs[rl][c]     = xin[offA];
  xs[rl + 4][c] = xin[offB];
  __syncthreads();
  float aqA = bq[c], akA = bk[c], avA = bv[c];
  float aqB = aqA,   akB = akA,   avB = avA;
  #pragma unroll
  for (int jj = 0; jj < DM; ++jj) {
    float wq_ = Wq[jj * DM + c], wk_ = Wk[jj * DM + c], wv_ = Wv[jj * DM + c];
    float xA = xs[rl][jj], xB = xs[rl + 4][jj];
    aqA = fmaf(xA, wq_, aqA); aqB = fmaf(xB, wq_, aqB);
    akA = fmaf(xA, wk_, akA); akB = fmaf(xB, wk_, akB);
    avA = fmaf(xA, wv_, avA); avB = fmaf(xB, wv_, avB);
  }
  float keepA = (protok[rA] != 0) ? 1.f : 0.f;
  float keepB = (protok[rB] != 0) ? 1.f : 0.f;
  qb[offA] = aqA * keepA * LOG2E;  qb[offB] = aqB * keepB * LOG2E;
  kb[offA] = akA * keepA;          kb[offB] = akB * keepB;
  vb[offA] = avA * keepA;          vb[offB] = avB * keepB;
}

// LDS layout (floats) for fast attention
#define FQS   0      // [256][8] = 2048
#define FVS   2048   // [256][8] = 2048
#define FKS   4096   // [256][9] = 2304
#define FRED  6400   // [32]
#define FPOOL 8448   // 33 KB

// ---- attention, shift-0 log2 domain, packed-fp32 FMA inner loop ----
__global__ __launch_bounds__(512, 4) void qkv_attn_fast(
    const float* __restrict__ qb, const float* __restrict__ kb,
    const float* __restrict__ vb, const int* __restrict__ protok,
    float* __restrict__ p0, float* __restrict__ p1,
    float* __restrict__ p2, float* __restrict__ p3,
    float* __restrict__ mt_out, float* __restrict__ s_out)
{
  int blk = blockIdx.x;
  int bh = blk >> 4, kc = (blk >> 2) & 3, qq = blk & 3;
  int b = bh >> 3, h = bh & 7;
  int t = threadIdx.x;
  __shared__ __align__(16) float pool[FPOOL];

  {
    int lr = t >> 1, hf = (t & 1) * 4;
    size_t qrow = (size_t)(b * LSEQ + qq * 256 + lr) * DM + h * 8 + hf;
    size_t krow = (size_t)(b * LSEQ + kc * 256 + lr) * DM + h * 8 + hf;
    *(float4*)&pool[FQS + lr * 8 + hf] = *(const float4*)&qb[qrow];
    *(float4*)&pool[FVS + lr * 8 + hf] = *(const float4*)&vb[qrow];
    *(float4*)&pool[FKS + lr * 9 + hf] = *(const float4*)&kb[krow];
  }
  __syncthreads();

  int wid = t >> 6, lane = t & 63;
  int j = wid, kg = lane;
  v2f krp[4][4];
  float pjm[4];
  #pragma unroll
  for (int kk = 0; kk < 4; ++kk) {
    #pragma unroll
    for (int i = 0; i < 4; ++i) {
      krp[kk][i][0] = pool[FKS + (kk*64+kg)*9 + 2*i];
      krp[kk][i][1] = pool[FKS + (kk*64+kg)*9 + 2*i + 1];
    }
    pjm[kk] = (protok[b*LSEQ + kc*256 + kk*64 + kg] != 0) ? 0.f : PAD2;
  }

  v2f acc2[4][4] = {};   // memory layout == float acc[4][8]
  float st = 0.f, mu_sh = -3.0e38f;
  int q0 = j * 32;
  for (int q = q0; q < q0 + 32; ++q) {
    v2f qp[4], vp[4];
    *(float4*)&qp[0] = *(const float4*)&pool[FQS + q*8];
    *(float4*)&qp[2] = *(const float4*)&pool[FQS + q*8 + 4];
    *(float4*)&vp[0] = *(const float4*)&pool[FVS + q*8];
    *(float4*)&vp[2] = *(const float4*)&pool[FVS + q*8 + 4];
    #pragma unroll
    for (int kk = 0; kk < 4; ++kk) {
      v2f d2 = {pjm[kk], 0.f};
      PKFMA(d2, qp[0], krp[kk][0]);
      PKFMA(d2, qp[1], krp[kk][1]);
      PKFMA(d2, qp[2], krp[kk][2]);
      PKFMA(d2, qp[3], krp[kk][3]);
      float d = d2[0] + d2[1];
      mu_sh = fmaxf(mu_sh, d);
      float e = EXP2(d);
      st += e;
      v2f e2 = {e, e};
      PKFMA(acc2[kk][0], e2, vp[0]);
      PKFMA(acc2[kk][1], e2, vp[1]);
      PKFMA(acc2[kk][2], e2, vp[2]);
      PKFMA(acc2[kk][3], e2, vp[3]);
    }
  }
  float* accf = (float*)acc2;
  __syncthreads();

  {
    float mw = wmax64(mu_sh), sw = wsum64(st);
    if (lane == 0) { pool[FRED + wid] = mw; pool[FRED + 16 + wid] = sw; }
  }
  __syncthreads();
  if (t == 0) {
    float m = pool[FRED], s = pool[FRED + 16];
    #pragma unroll
    for (int i = 1; i < 8; ++i) {
      m = fmaxf(m, pool[FRED + i]);
      s += pool[FRED + 16 + i];
    }
    mt_out[blk] = m; s_out[blk] = s;
  }
  __syncthreads();

#define MWRITE(DW) { _Pragma("unroll") for (int kk = 0; kk < 4; ++kk) \
    { _Pragma("unroll") for (int dd = 0; dd < 8; ++dd) \
      pool[(DW)*2112 + kg*33 + kk*8 + dd] = accf[kk*8 + dd]; } }
#define MADD(SW) { _Pragma("unroll") for (int kk = 0; kk < 4; ++kk) \
    { _Pragma("unroll") for (int dd = 0; dd < 8; ++dd) \
      accf[kk*8 + dd] += pool[(SW)*2112 + kg*33 + kk*8 + dd]; } }
  if (j >= 4) MWRITE(j - 4);
  __syncthreads();
  if (j < 4) MADD(j);
  __syncthreads();
  if (j == 2 || j == 3) MWRITE(j - 2);
  __syncthreads();
  if (j < 2) MADD(j);
  __syncthreads();
  if (j == 1) MWRITE(0);
  __syncthreads();
  if (j == 0) {
    MADD(0);
    float* part = (qq == 0) ? p0 : (qq == 1) ? p1 : (qq == 2) ? p2 : p3;
    #pragma unroll
    for (int kk = 0; kk < 4; ++kk) {
      float* dst = &part[((size_t)(b*LSEQ + kc*256 + kk*64 + kg))*DM + h*8];
      *(float4*)dst     = make_float4(accf[kk*8+0], accf[kk*8+1], accf[kk*8+2], accf[kk*8+3]);
      *(float4*)(dst+4) = make_float4(accf[kk*8+4], accf[kk*8+5], accf[kk*8+6], accf[kk*8+7]);
    }
  }
#undef MWRITE
#undef MADD
}

// ---- fused tail, 2 rows/thread (round-12 proven) ----
__global__ __launch_bounds__(256, 4) void tail_fast(
    const float* __restrict__ p0, const float* __restrict__ p1,
    const float* __restrict__ p2, const float* __restrict__ p3,
    const float* __restrict__ mt, const float* __restrict__ sp,
    const float* __restrict__ nzb,
    const float* __restrict__ Wo, const float* __restrict__ bo,
    const float* __restrict__ xin,
    const float* __restrict__ g1, const float* __restrict__ be1,
    const float* __restrict__ W1, const float* __restrict__ b1,
    const float* __restrict__ W2, const float* __restrict__ b2,
    const float* __restrict__ g2, const float* __restrict__ be2,
    const int* __restrict__ protok, float* __restrict__ xout)
{
  int t = threadIdx.x, rl = t >> 6, c = t & 63;
  int r0 = blockIdx.x * 8;
  int rA = r0 + rl, rB = rA + 4;
  __shared__ float As[8][64];
  __shared__ float h1s[8][DFF];

  float mmax = -3.0e38f, ssum = 0.f;
  #pragma unroll
  for (int i = 0; i < 16; ++i) {
    mmax = fmaxf(mmax, mt[c*16 + i]);
    ssum += sp[c*16 + i];
  }
  float ratio = nzb[c >> 3] / ssum;
  float gm = wmax64(ratio * EXP2(mmax));
  int bh = ((rA >> 10) << 3) + (c >> 3);
  float cs = __shfl(ratio, bh) / gm;

  size_t offA = (size_t)rA * DM + c, offB = (size_t)rB * DM + c;
  As[rl][c]     = (p0[offA] + p1[offA] + p2[offA] + p3[offA]) * cs;
  As[rl + 4][c] = (p0[offB] + p1[offB] + p2[offB] + p3[offB]) * cs;
  __syncthreads();
  float aA = bo[c], aB = bo[c];
  #pragma unroll
  for (int jj = 0; jj < DM; ++jj) {
    float w = Wo[jj * DM + c];
    aA = fmaf(As[rl][jj],     w, aA);
    aB = fmaf(As[rl + 4][jj], w, aB);
  }
  float keepA = (protok[rA] != 0) ? 1.f : 0.f;
  float keepB = (protok[rB] != 0) ? 1.f : 0.f;
  float vA = xin[offA] + aA * keepA;
  float vB = xin[offB] + aB * keepB;
  float muA = wsum64(vA) * 0.015625f;
  float muB = wsum64(vB) * 0.015625f;
  float dA = vA - muA, dB = vB - muB;
  float varA = wsum64(dA * dA) * 0.015625f;
  float varB = wsum64(dB * dB) * 0.015625f;
  float o1A = (dA * rsqrtf(varA + 1e-9f) * g1[c] + be1[c]) * keepA;
  float o1B = (dB * rsqrtf(varB + 1e-9f) * g1[c] + be1[c]) * keepB;
  __syncthreads();
  As[rl][c] = o1A;
  As[rl + 4][c] = o1B;
  __syncthreads();
  #pragma unroll
  for (int s = 0; s < 4; ++s) {
    int col = c + 64 * s;
    float a1A = b1[col], a1B = b1[col];
    #pragma unroll
    for (int jj = 0; jj < DM; ++jj) {
      float w = W1[jj * DFF + col];
      a1A = fmaf(As[rl][jj],     w, a1A);
      a1B = fmaf(As[rl + 4][jj], w, a1B);
    }
    h1s[rl][col]     = fmaxf(a1A, 0.f);
    h1s[rl + 4][col] = fmaxf(a1B, 0.f);
  }
  __syncthreads();
  float a2A = b2[c], a2B = b2[c];
  #pragma unroll 8
  for (int jj = 0; jj < DFF; ++jj) {
    float w = W2[jj * DM + c];
    a2A = fmaf(h1s[rl][jj],     w, a2A);
    a2B = fmaf(h1s[rl + 4][jj], w, a2B);
  }
  vA = o1A + a2A * keepA;
  vB = o1B + a2B * keepB;
  muA = wsum64(vA) * 0.015625f;
  muB = wsum64(vB) * 0.015625f;
  dA = vA - muA; dB = vB - muB;
  varA = wsum64(dA * dA) * 0.015625f;
  varB = wsum64(dB * dB) * 0.015625f;
  xout[offA] = (dA * rsqrtf(varA + 1e-9f) * g2[c] + be2[c]) * keepA;
  xout[offB] = (dB * rsqrtf(varB + 1e-9f) * g2[c] + be2[c]) * keepB;
}

// ================== SAFE PATH ==================

#define QS_OFF   0
#define VS_OFF   4096
#define KS_OFF   8192
#define WS_OFF   10496
#define XSG_OFF  12032
#define RED_OFF  16640
#define POOL_SZ  16672

__global__ __launch_bounds__(512, 4) void qkv_attn_safe(
    const float* __restrict__ xin, const int* __restrict__ protok,
    const float* __restrict__ Wq, const float* __restrict__ bq,
    const float* __restrict__ Wk, const float* __restrict__ bk,
    const float* __restrict__ Wv, const float* __restrict__ bv,
    float* __restrict__ part0, float* __restrict__ part1,
    float* __restrict__ mh_out, float* __restrict__ mt_out, float* __restrict__ s_out)
{
  int blk = blockIdx.x;
  int bh = blk >> 3, kc = (blk >> 1) & 3, qh = blk & 1;
  int b = bh >> 3, h = bh & 7;
  int t = threadIdx.x;
  __shared__ __align__(16) float pool[POOL_SZ];
  {
    int jj = t >> 3, c8 = t & 7;
    pool[WS_OFF + t]        = Wq[jj * DM + h * 8 + c8];
    pool[WS_OFF + 512 + t]  = Wk[jj * DM + h * 8 + c8];
    pool[WS_OFF + 1024 + t] = Wv[jj * DM + h * 8 + c8];
  }
  int cc = t & 7, prow = t >> 3;
  float bqv = bq[h*8+cc], bkv = bk[h*8+cc], bvv = bv[h*8+cc];
  __syncthreads();
  float qn2max = 0.f, kn2max = 0.f;
  for (int ch = 0; ch < 12; ++ch) {
    int gr0 = (ch < 8) ? (qh*512 + ch*64) : (kc*256 + (ch-8)*64);
    {
      int i = t >> 3, c8 = (t & 7) * 8;
      const float4* p = (const float4*)&xin[((size_t)(b*LSEQ + gr0 + i))*DM + c8];
      float4 p0 = p[0], p1 = p[1];
      *(float4*)&pool[XSG_OFF + i*72 + c8]     = p0;
      *(float4*)&pool[XSG_OFF + i*72 + c8 + 4] = p1;
    }
    __syncthreads();
    float keep = (protok[b*LSEQ + gr0 + prow] != 0) ? 1.f : 0.f;
    if (ch < 8) {
      float aq = bqv, av = bvv;
      #pragma unroll
      for (int jj = 0; jj < DM; ++jj) {
        float xv = pool[XSG_OFF + prow*72 + jj];
        aq = fmaf(xv, pool[WS_OFF + jj*8 + cc], aq);
        av = fmaf(xv, pool[WS_OFF + 1024 + jj*8 + cc], av);
      }
      aq *= keep * LOG2E;
      av *= keep;
      int lq = ch*64 + prow;
      pool[QS_OFF + lq*8 + cc] = aq;
      pool[VS_OFF + lq*8 + cc] = av;
      float s2 = aq * aq;
      s2 += __shfl_xor(s2, 1); s2 += __shfl_xor(s2, 2); s2 += __shfl_xor(s2, 4);
      qn2max = fmaxf(qn2max, s2);
    } else {
      float ak = bkv;
      #pragma unroll
      for (int jj = 0; jj < DM; ++jj)
        ak = fmaf(pool[XSG_OFF + prow*72 + jj], pool[WS_OFF + 512 + jj*8 + cc], ak);
      ak *= keep;
      int lk = (ch-8)*64 + prow;
      pool[KS_OFF + lk*9 + cc] = ak;
      float k2 = ak * ak;
      k2 += __shfl_xor(k2, 1); k2 += __shfl_xor(k2, 2); k2 += __shfl_xor(k2, 4);
      kn2max = fmaxf(kn2max, k2);
    }
    __syncthreads();
  }
  int wid = t >> 6, lane = t & 63;
  {
    float qm = wmax64(qn2max), km = wmax64(kn2max);
    if (lane == 0) { pool[RED_OFF + wid] = qm; pool[RED_OFF + 16 + wid] = km; }
  }
  __syncthreads();
  float qn2 = pool[RED_OFF], kn2 = pool[RED_OFF + 16];
  #pragma unroll
  for (int i = 1; i < 8; ++i) {
    qn2 = fmaxf(qn2, pool[RED_OFF + i]);
    kn2 = fmaxf(kn2, pool[RED_OFF + 16 + i]);
  }
  float mhat = sqrtf(qn2 * kn2);
  __syncthreads();
  int j = wid, kg = lane;
  float kr[4][8], pjm[4];
  #pragma unroll
  for (int kk = 0; kk < 4; ++kk) {
    #pragma unroll
    for (int dd = 0; dd < 8; ++dd) kr[kk][dd] = pool[KS_OFF + (kk*64+kg)*9 + dd];
    pjm[kk] = ((protok[b*LSEQ + kc*256 + kk*64 + kg] != 0) ? 0.f : -1.0e9f) - mhat;
  }
  float acc[4][8] = {};
  float st = 0.f, mu_sh = -3.0e38f;
  int q0 = j * 64;
  for (int q = q0; q < q0 + 64; ++q) {
    float4 a  = *(const float4*)&pool[QS_OFF + q*8];
    float4 b4 = *(const float4*)&pool[QS_OFF + q*8 + 4];
    float4 c0 = *(const float4*)&pool[VS_OFF + q*8];
    float4 c1 = *(const float4*)&pool[VS_OFF + q*8 + 4];
    float qv[8] = {a.x,a.y,a.z,a.w,b4.x,b4.y,b4.z,b4.w};
    float vv[8] = {c0.x,c0.y,c0.z,c0.w,c1.x,c1.y,c1.z,c1.w};
    #pragma unroll
    for (int kk = 0; kk < 4; ++kk) {
      float d = pjm[kk];
      #pragma unroll
      for (int dd = 0; dd < 8; ++dd) d = fmaf(qv[dd], kr[kk][dd], d);
      mu_sh = fmaxf(mu_sh, d);
      float e = EXP2(d);
      st += e;
      #pragma unroll
      for (int dd = 0; dd < 8; ++dd) acc[kk][dd] = fmaf(e, vv[dd], acc[kk][dd]);
    }
  }
  __syncthreads();
  {
    float mw = wmax64(mu_sh), sw = wsum64(st);
    if (lane == 0) { pool[RED_OFF + wid] = mw; pool[RED_OFF + 16 + wid] = sw; }
  }
  __syncthreads();
  if (t == 0) {
    float m = pool[RED_OFF], s = pool[RED_OFF + 16];
    #pragma unroll
    for (int i = 1; i < 8; ++i) {
      m = fmaxf(m, pool[RED_OFF + i]);
      s += pool[RED_OFF + 16 + i];
    }
    s_out[blk] = s; mh_out[blk] = mhat; mt_out[blk] = m + mhat;
  }
  __syncthreads();
#define MWRITE(DW) { _Pragma("unroll") for (int kk = 0; kk < 4; ++kk) \
    { _Pragma("unroll") for (int dd = 0; dd < 8; ++dd) \
      pool[(DW)*2112 + kg*33 + kk*8 + dd] = acc[kk][dd]; } }
#define MADD(SW) { _Pragma("unroll") for (int kk = 0; kk < 4; ++kk) \
    { _Pragma("unroll") for (int dd = 0; dd < 8; ++dd) \
      acc[kk][dd] += pool[(SW)*2112 + kg*33 + kk*8 + dd]; } }
  if (j >= 4) MWRITE(j - 4);
  __syncthreads();
  if (j < 4) MADD(j);
  __syncthreads();
  if (j == 2 || j == 3) MWRITE(j - 2);
  __syncthreads();
  if (j < 2) MADD(j);
  __syncthreads();
  if (j == 1) MWRITE(0);
  __syncthreads();
  if (j == 0) {
    MADD(0);
    float* part = qh ? part1 : part0;
    #pragma unroll
    for (int kk = 0; kk < 4; ++kk) {
      float* dst = &part[((size_t)(b*LSEQ + kc*256 + kk*64 + kg))*DM + h*8];
      *(float4*)dst     = make_float4(acc[kk][0], acc[kk][1], acc[kk][2], acc[kk][3]);
      *(float4*)(dst+4) = make_float4(acc[kk][4], acc[kk][5], acc[kk][6], acc[kk][7]);
    }
  }
#undef MWRITE
#undef MADD
}

__global__ void attn_combine(const float* __restrict__ mh, const float* __restrict__ mt,
                             const float* __restrict__ sp, const float* __restrict__ nz,
                             float* __restrict__ cs){
  int bh = threadIdx.x;
  float mhl[8], sl[8];
  float mu = -3.0e38f;
  #pragma unroll
  for (int i = 0; i < 8; ++i) {
    mhl[i] = mh[bh*8+i]; sl[i] = sp[bh*8+i];
    mu = fmaxf(mu, mt[bh*8+i]);
  }
  float S = 0.f;
  #pragma unroll
  for (int i = 0; i < 8; ++i) S += sl[i] * EXP2(mhl[i] - mu);
  float w = nz[bh >> 3] / S;
  float gm = wmax64(w);
  float c = w / gm;
  #pragma unroll
  for (int i = 0; i < 8; ++i) cs[i*64 + bh] = c * EXP2(mhl[i] - mu);
}

__global__ __launch_bounds__(512) void oproj_ln(
    float* part0, const float* __restrict__ part1, const float* __restrict__ cs,
    const float* __restrict__ Wo, const float* __restrict__ bo,
    const float* __restrict__ xin, const float* __restrict__ g,
    const float* __restrict__ be, const int* __restrict__ protok)
{
  int tid = threadIdx.x, rl = tid >> 6, c = tid & 63;
  int r = blockIdx.x * 8 + rl;
  int bh = ((r >> 10) << 3) + (c >> 3);
  int kc = (r >> 8) & 3;
  __shared__ float As[8][64];
  float cs0 = cs[(kc*2)*64 + bh], cs1 = cs[(kc*2+1)*64 + bh];
  As[rl][c] = part0[(size_t)r * DM + c] * cs0 + part1[(size_t)r * DM + c] * cs1;
  __syncthreads();
  float acc = bo[c];
  #pragma unroll
  for (int jj = 0; jj < DM; ++jj) acc = fmaf(As[rl][jj], Wo[jj * DM + c], acc);
  float keep = (protok[r] != 0) ? 1.f : 0.f;
  float v = xin[(size_t)r * DM + c] + acc * keep;
  float mu = wsum64(v) * 0.015625f;
  float d = v - mu;
  float var = wsum64(d * d) * 0.015625f;
  float o = d * rsqrtf(var + 1e-9f) * g[c] + be[c];
  part0[(size_t)r * DM + c] = o * keep;
}

__global__ __launch_bounds__(512) void ffn_ln(
    const float* __restrict__ out1,
    const float* __restrict__ W1, const float* __restrict__ b1,
    const float* __restrict__ W2, const float* __restrict__ b2,
    const float* __restrict__ g, const float* __restrict__ be,
    const int* __restrict__ protok, float* __restrict__ xout)
{
  int tid = threadIdx.x, rl = tid >> 6, c = tid & 63;
  int r = blockIdx.x * 8 + rl;
  __shared__ float xs[8][64];
  __shared__ float h1s[8][DFF];
  xs[rl][c] = out1[(size_t)r * DM + c];
  __syncthreads();
  #pragma unroll
  for (int s = 0; s < 4; ++s) {
    int col = c + 64 * s;
    float a = b1[col];
    #pragma unroll
    for (int jj = 0; jj < DM; ++jj) a = fmaf(xs[rl][jj], W1[jj * DFF + col], a);
    h1s[rl][col] = fmaxf(a, 0.f);
  }
  __syncthreads();
  float a2 = b2[c];
  #pragma unroll 8
  for (int jj = 0; jj < DFF; ++jj) a2 = fmaf(h1s[rl][jj], W2[jj * DM + c], a2);
  float keep = (protok[r] != 0) ? 1.f : 0.f;
  float v = xs[rl][c] + a2 * keep;
  float mu = wsum64(v) * 0.015625f;
  float d = v - mu;
  float var = wsum64(d * d) * 0.015625f;
  float o = d * rsqrtf(var + 1e-9f) * g[c] + be[c];
  xout[(size_t)r * DM + c] = o * keep;
}

extern "C" void kernel_launch(void* const* d_in, const int* in_sizes, int n_in,
                              void* d_out, int out_size, void* d_ws, size_t ws_size,
                              hipStream_t stream) {
  const float* x      = (const float*)d_in[0];
  const int*   protok = (const int*)d_in[1];
  const float* Wq = (const float*)d_in[2];  const float* bq = (const float*)d_in[3];
  const float* Wk = (const float*)d_in[4];  const float* bk = (const float*)d_in[5];
  const float* Wv = (const float*)d_in[6];  const float* bv = (const float*)d_in[7];
  const float* Wo = (const float*)d_in[8];  const float* bo = (const float*)d_in[9];
  const float* W1 = (const float*)d_in[10]; const float* b1 = (const float*)d_in[11];
  const float* W2 = (const float*)d_in[12]; const float* b2 = (const float*)d_in[13];
  const float* g1 = (const float*)d_in[14]; const float* be1 = (const float*)d_in[15];
  const float* g2 = (const float*)d_in[16]; const float* be2 = (const float*)d_in[17];

  const size_t N = (size_t)NROW * DM;   // 524288
  const size_t fast_need = (7 * N + 4096) * sizeof(float);   // ~14.7 MB
  bool fast = (ws_size >= fast_need);

  nz_kernel<<<NB, 1024, 0, stream>>>(protok, (float*)d_ws + (fast ? 7*N : 2*N + 2048));

  if (fast) {
    float* xf   = (float*)d_ws;         // N
    float* po   = xf + N;               // N (p0)
    float* p2   = po + N;               // N
    float* p3   = p2 + N;               // N
    float* qbuf = p3 + N;               // N
    float* kbuf = qbuf + N;             // N
    float* vbuf = kbuf + N;             // N
    float* nzb  = vbuf + N;             // 8
    float* mtb  = nzb + 16;             // 1024
    float* spb  = mtb + 1024;           // 1024
    float* p1   = (float*)d_out;        // N (scratch slab; final tail overwrites)

    for (int l = 0; l < NLAYER; ++l) {
      const float* Wq_l = Wq + (size_t)l*DM*DM;  const float* bq_l = bq + (size_t)l*DM;
      const float* Wk_l = Wk + (size_t)l*DM*DM;  const float* bk_l = bk + (size_t)l*DM;
      const float* Wv_l = Wv + (size_t)l*DM*DM;  const float* bv_l = bv + (size_t)l*DM;
      const float* Wo_l = Wo + (size_t)l*DM*DM;  const float* bo_l = bo + (size_t)l*DM;
      const float* W1_l = W1 + (size_t)l*DM*DFF; const float* b1_l = b1 + (size_t)l*DFF;
      const float* W2_l = W2 + (size_t)l*DFF*DM; const float* b2_l = b2 + (size_t)l*DM;
      const float* g1_l = g1 + (size_t)l*DM;  const float* be1_l = be1 + (size_t)l*DM;
      const float* g2_l = g2 + (size_t)l*DM;  const float* be2_l = be2 + (size_t)l*DM;
      const float* xin = (l == 0) ? x : xf;
      float* xout = (l == NLAYER - 1) ? (float*)d_out : xf;

      qkv_proj<<<NROW/8, 256, 0, stream>>>(xin, protok, Wq_l, bq_l, Wk_l, bk_l,
                                           Wv_l, bv_l, qbuf, kbuf, vbuf);
      qkv_attn_fast<<<1024, 512, 0, stream>>>(qbuf, kbuf, vbuf, protok,
                                              po, p1, p2, p3, mtb, spb);
      tail_fast<<<NROW/8, 256, 0, stream>>>(po, p1, p2, p3, mtb, spb, nzb,
                                            Wo_l, bo_l, xin, g1_l, be1_l,
                                            W1_l, b1_l, W2_l, b2_l, g2_l, be2_l,
                                            protok, xout);
    }
  } else {
    float* xf   = (float*)d_ws;
    float* po   = xf + N;
    float* nzb  = po + N + 2048;
    float* mh   = nzb + 8;
    float* mt   = mh + 512;
    float* sp   = mt + 512;
    float* cs   = sp + 512;
    float* p1   = (float*)d_out;

    for (int l = 0; l < NLAYER; ++l) {
      const float* Wq_l = Wq + (size_t)l*DM*DM;  const float* bq_l = bq + (size_t)l*DM;
      const float* Wk_l = Wk + (size_t)l*DM*DM;  const float* bk_l = bk + (size_t)l*DM;
      const float* Wv_l = Wv + (size_t)l*DM*DM;  const float* bv_l = bv + (size_t)l*DM;
      const float* Wo_l = Wo + (size_t)l*DM*DM;  const float* bo_l = bo + (size_t)l*DM;
      const float* W1_l = W1 + (size_t)l*DM*DFF; const float* b1_l = b1 + (size_t)l*DFF;
      const float* W2_l = W2 + (size_t)l*DFF*DM; const float* b2_l = b2 + (size_t)l*DM;
      const float* g1_l = g1 + (size_t)l*DM;  const float* be1_l = be1 + (size_t)l*DM;
      const float* g2_l = g2 + (size_t)l*DM;  const float* be2_l = be2 + (size_t)l*DM;
      const float* xin = (l == 0) ? x : xf;
      float* xout = (l == NLAYER - 1) ? (float*)d_out : xf;

      qkv_attn_safe<<<512, 512, 0, stream>>>(xin, protok, Wq_l, bq_l, Wk_l, bk_l,
                                             Wv_l, bv_l, po, p1, mh, mt, sp);
      attn_combine<<<1, 64, 0, stream>>>(mh, mt, sp, nzb, cs);
      oproj_ln<<<NROW/8, 512, 0, stream>>>(po, p1, cs, Wo_l, bo_l, xin, g1_l, be1_l, protok);
      ffn_ln<<<NROW/8, 512, 0, stream>>>(po, W1_l, b1_l, W2_l, b2_l, g2_l, be2_l, protok, xout);
    }
  }
}

// Round 16
// 295.395 us; speedup vs baseline: 1.0634x; 1.0634x over previous
//
#include <hip/hip_runtime.h>

#define NB 8
#define LSEQ 1024
#define DM 64
#define DFF 256
#define NLAYER 4
#define NROW (NB*LSEQ)
#define LOG2E 1.44269504088896f
#define PAD2  (-1.442695e9f)
#define EXP2(x) __builtin_amdgcn_exp2f(x)

__device__ __forceinline__ float wsum64(float v){
  #pragma unroll
  for (int off = 32; off; off >>= 1) v += __shfl_xor(v, off);
  return v;
}
__device__ __forceinline__ float wmax64(float v){
  #pragma unroll
  for (int off = 32; off; off >>= 1) v = fmaxf(v, __shfl_xor(v, off));
  return v;
}

// ---- nz per batch ----
__global__ void nz_kernel(const int* __restrict__ protok, float* __restrict__ nz){
  __shared__ float sm[16];
  int t = threadIdx.x;
  float v = (protok[blockIdx.x * LSEQ + t] != 0) ? 1.f : 0.f;
  v = wsum64(v);
  if ((t & 63) == 0) sm[t >> 6] = v;
  __syncthreads();
  if (t < 16){
    float s = sm[t];
    #pragma unroll
    for (int off = 8; off; off >>= 1) s += __shfl_xor(s, off);
    if (t == 0) nz[blockIdx.x] = s;
  }
}

// ================== FAST PATH ==================

// ---- QKV projection, 2 rows/thread (round-12 proven) ----
__global__ __launch_bounds__(256, 4) void qkv_proj(
    const float* __restrict__ xin, const int* __restrict__ protok,
    const float* __restrict__ Wq, const float* __restrict__ bq,
    const float* __restrict__ Wk, const float* __restrict__ bk,
    const float* __restrict__ Wv, const float* __restrict__ bv,
    float* __restrict__ qb, float* __restrict__ kb, float* __restrict__ vb)
{
  int t = threadIdx.x, rl = t >> 6, c = t & 63;
  int r0 = blockIdx.x * 8;
  int rA = r0 + rl, rB = rA + 4;
  size_t offA = (size_t)rA * DM + c, offB = (size_t)rB * DM + c;
  __shared__ float xs[8][64];
  xs[rl][c]     = xin[offA];
  xs[rl + 4][c] = xin[offB];
  __syncthreads();
  float aqA = bq[c], akA = bk[c], avA = bv[c];
  float aqB = aqA,   akB = akA,   avB = avA;
  #pragma unroll
  for (int jj = 0; jj < DM; ++jj) {
    float wq_ = Wq[jj * DM + c], wk_ = Wk[jj * DM + c], wv_ = Wv[jj * DM + c];
    float xA = xs[rl][jj], xB = xs[rl + 4][jj];
    aqA = fmaf(xA, wq_, aqA); aqB = fmaf(xB, wq_, aqB);
    akA = fmaf(xA, wk_, akA); akB = fmaf(xB, wk_, akB);
    avA = fmaf(xA, wv_, avA); avB = fmaf(xB, wv_, avB);
  }
  float keepA = (protok[rA] != 0) ? 1.f : 0.f;
  float keepB = (protok[rB] != 0) ? 1.f : 0.f;
  qb[offA] = aqA * keepA * LOG2E;  qb[offB] = aqB * keepB * LOG2E;
  kb[offA] = akA * keepA;          kb[offB] = akB * keepB;
  vb[offA] = avA * keepA;          vb[offB] = avB * keepB;
}

// LDS layout (floats) for fast attention
#define FQS   0      // [256][8] = 2048
#define FVS   2048   // [256][8] = 2048
#define FKS   4096   // [256][9] = 2304
#define FRED  6400   // [32]
#define FPOOL 8448   // 33 KB

// ---- attention, shift-0 log2 domain; XCD-swizzled grid; split dot chains ----
__global__ __launch_bounds__(512, 4) void qkv_attn_fast(
    const float* __restrict__ qb, const float* __restrict__ kb,
    const float* __restrict__ vb, const int* __restrict__ protok,
    float* __restrict__ p0, float* __restrict__ p1,
    float* __restrict__ p2, float* __restrict__ p3,
    float* __restrict__ mt_out, float* __restrict__ s_out)
{
  // XCD swizzle: all 16 blocks of one (b,h) land on one XCD (1024 = 8 x 128)
  int blk = ((blockIdx.x & 7) << 7) | (blockIdx.x >> 3);
  int bh = blk >> 4, kc = (blk >> 2) & 3, qq = blk & 3;
  int b = bh >> 3, h = bh & 7;
  int t = threadIdx.x;
  __shared__ __align__(16) float pool[FPOOL];

  {
    int lr = t >> 1, hf = (t & 1) * 4;
    size_t qrow = (size_t)(b * LSEQ + qq * 256 + lr) * DM + h * 8 + hf;
    size_t krow = (size_t)(b * LSEQ + kc * 256 + lr) * DM + h * 8 + hf;
    *(float4*)&pool[FQS + lr * 8 + hf] = *(const float4*)&qb[qrow];
    *(float4*)&pool[FVS + lr * 8 + hf] = *(const float4*)&vb[qrow];
    *(float4*)&pool[FKS + lr * 9 + hf] = *(const float4*)&kb[krow];
  }
  __syncthreads();

  int wid = t >> 6, lane = t & 63;
  int j = wid, kg = lane;
  float kr[4][8], pjm[4];
  #pragma unroll
  for (int kk = 0; kk < 4; ++kk) {
    #pragma unroll
    for (int dd = 0; dd < 8; ++dd) kr[kk][dd] = pool[FKS + (kk*64+kg)*9 + dd];
    pjm[kk] = (protok[b*LSEQ + kc*256 + kk*64 + kg] != 0) ? 0.f : PAD2;
  }

  float acc[4][8] = {};
  float st0 = 0.f, st1 = 0.f, mu_sh = -3.0e38f;
  int q0 = j * 32;
  for (int q = q0; q < q0 + 32; ++q) {
    float4 a  = *(const float4*)&pool[FQS + q*8];
    float4 b4 = *(const float4*)&pool[FQS + q*8 + 4];
    float4 c0 = *(const float4*)&pool[FVS + q*8];
    float4 c1 = *(const float4*)&pool[FVS + q*8 + 4];
    float qv[8] = {a.x,a.y,a.z,a.w,b4.x,b4.y,b4.z,b4.w};
    float vv[8] = {c0.x,c0.y,c0.z,c0.w,c1.x,c1.y,c1.z,c1.w};
    #pragma unroll
    for (int kk = 0; kk < 4; ++kk) {
      float d0 = pjm[kk], d1 = 0.f;
      d0 = fmaf(qv[0], kr[kk][0], d0); d1 = fmaf(qv[1], kr[kk][1], d1);
      d0 = fmaf(qv[2], kr[kk][2], d0); d1 = fmaf(qv[3], kr[kk][3], d1);
      d0 = fmaf(qv[4], kr[kk][4], d0); d1 = fmaf(qv[5], kr[kk][5], d1);
      d0 = fmaf(qv[6], kr[kk][6], d0); d1 = fmaf(qv[7], kr[kk][7], d1);
      float d = d0 + d1;
      mu_sh = fmaxf(mu_sh, d);
      float e = EXP2(d);
      if (kk & 1) st1 += e; else st0 += e;
      #pragma unroll
      for (int dd = 0; dd < 8; ++dd) acc[kk][dd] = fmaf(e, vv[dd], acc[kk][dd]);
    }
  }
  float st = st0 + st1;
  __syncthreads();

  {
    float mw = wmax64(mu_sh), sw = wsum64(st);
    if (lane == 0) { pool[FRED + wid] = mw; pool[FRED + 16 + wid] = sw; }
  }
  __syncthreads();
  if (t == 0) {
    float m = pool[FRED], s = pool[FRED + 16];
    #pragma unroll
    for (int i = 1; i < 8; ++i) {
      m = fmaxf(m, pool[FRED + i]);
      s += pool[FRED + 16 + i];
    }
    mt_out[blk] = m; s_out[blk] = s;
  }
  __syncthreads();

#define MWRITE(DW) { _Pragma("unroll") for (int kk = 0; kk < 4; ++kk) \
    { _Pragma("unroll") for (int dd = 0; dd < 8; ++dd) \
      pool[(DW)*2112 + kg*33 + kk*8 + dd] = acc[kk][dd]; } }
#define MADD(SW) { _Pragma("unroll") for (int kk = 0; kk < 4; ++kk) \
    { _Pragma("unroll") for (int dd = 0; dd < 8; ++dd) \
      acc[kk][dd] += pool[(SW)*2112 + kg*33 + kk*8 + dd]; } }
  if (j >= 4) MWRITE(j - 4);
  __syncthreads();
  if (j < 4) MADD(j);
  __syncthreads();
  if (j == 2 || j == 3) MWRITE(j - 2);
  __syncthreads();
  if (j < 2) MADD(j);
  __syncthreads();
  if (j == 1) MWRITE(0);
  __syncthreads();
  if (j == 0) {
    MADD(0);
    float* part = (qq == 0) ? p0 : (qq == 1) ? p1 : (qq == 2) ? p2 : p3;
    #pragma unroll
    for (int kk = 0; kk < 4; ++kk) {
      float* dst = &part[((size_t)(b*LSEQ + kc*256 + kk*64 + kg))*DM + h*8];
      *(float4*)dst     = make_float4(acc[kk][0], acc[kk][1], acc[kk][2], acc[kk][3]);
      *(float4*)(dst+4) = make_float4(acc[kk][4], acc[kk][5], acc[kk][6], acc[kk][7]);
    }
  }
#undef MWRITE
#undef MADD
}

// ---- fused tail, 2 rows/thread (round-12 proven) ----
__global__ __launch_bounds__(256, 4) void tail_fast(
    const float* __restrict__ p0, const float* __restrict__ p1,
    const float* __restrict__ p2, const float* __restrict__ p3,
    const float* __restrict__ mt, const float* __restrict__ sp,
    const float* __restrict__ nzb,
    const float* __restrict__ Wo, const float* __restrict__ bo,
    const float* __restrict__ xin,
    const float* __restrict__ g1, const float* __restrict__ be1,
    const float* __restrict__ W1, const float* __restrict__ b1,
    const float* __restrict__ W2, const float* __restrict__ b2,
    const float* __restrict__ g2, const float* __restrict__ be2,
    const int* __restrict__ protok, float* __restrict__ xout)
{
  int t = threadIdx.x, rl = t >> 6, c = t & 63;
  int r0 = blockIdx.x * 8;
  int rA = r0 + rl, rB = rA + 4;
  __shared__ float As[8][64];
  __shared__ float h1s[8][DFF];

  float mmax = -3.0e38f, ssum = 0.f;
  #pragma unroll
  for (int i = 0; i < 16; ++i) {
    mmax = fmaxf(mmax, mt[c*16 + i]);
    ssum += sp[c*16 + i];
  }
  float ratio = nzb[c >> 3] / ssum;
  float gm = wmax64(ratio * EXP2(mmax));
  int bh = ((rA >> 10) << 3) + (c >> 3);
  float cs = __shfl(ratio, bh) / gm;

  size_t offA = (size_t)rA * DM + c, offB = (size_t)rB * DM + c;
  As[rl][c]     = (p0[offA] + p1[offA] + p2[offA] + p3[offA]) * cs;
  As[rl + 4][c] = (p0[offB] + p1[offB] + p2[offB] + p3[offB]) * cs;
  __syncthreads();
  float aA = bo[c], aB = bo[c];
  #pragma unroll
  for (int jj = 0; jj < DM; ++jj) {
    float w = Wo[jj * DM + c];
    aA = fmaf(As[rl][jj],     w, aA);
    aB = fmaf(As[rl + 4][jj], w, aB);
  }
  float keepA = (protok[rA] != 0) ? 1.f : 0.f;
  float keepB = (protok[rB] != 0) ? 1.f : 0.f;
  float vA = xin[offA] + aA * keepA;
  float vB = xin[offB] + aB * keepB;
  float muA = wsum64(vA) * 0.015625f;
  float muB = wsum64(vB) * 0.015625f;
  float dA = vA - muA, dB = vB - muB;
  float varA = wsum64(dA * dA) * 0.015625f;
  float varB = wsum64(dB * dB) * 0.015625f;
  float o1A = (dA * rsqrtf(varA + 1e-9f) * g1[c] + be1[c]) * keepA;
  float o1B = (dB * rsqrtf(varB + 1e-9f) * g1[c] + be1[c]) * keepB;
  __syncthreads();
  As[rl][c] = o1A;
  As[rl + 4][c] = o1B;
  __syncthreads();
  #pragma unroll
  for (int s = 0; s < 4; ++s) {
    int col = c + 64 * s;
    float a1A = b1[col], a1B = b1[col];
    #pragma unroll
    for (int jj = 0; jj < DM; ++jj) {
      float w = W1[jj * DFF + col];
      a1A = fmaf(As[rl][jj],     w, a1A);
      a1B = fmaf(As[rl + 4][jj], w, a1B);
    }
    h1s[rl][col]     = fmaxf(a1A, 0.f);
    h1s[rl + 4][col] = fmaxf(a1B, 0.f);
  }
  __syncthreads();
  float a2A = b2[c], a2B = b2[c];
  #pragma unroll 8
  for (int jj = 0; jj < DFF; ++jj) {
    float w = W2[jj * DM + c];
    a2A = fmaf(h1s[rl][jj],     w, a2A);
    a2B = fmaf(h1s[rl + 4][jj], w, a2B);
  }
  vA = o1A + a2A * keepA;
  vB = o1B + a2B * keepB;
  muA = wsum64(vA) * 0.015625f;
  muB = wsum64(vB) * 0.015625f;
  dA = vA - muA; dB = vB - muB;
  varA = wsum64(dA * dA) * 0.015625f;
  varB = wsum64(dB * dB) * 0.015625f;
  xout[offA] = (dA * rsqrtf(varA + 1e-9f) * g2[c] + be2[c]) * keepA;
  xout[offB] = (dB * rsqrtf(varB + 1e-9f) * g2[c] + be2[c]) * keepB;
}

// ================== SAFE PATH ==================

#define QS_OFF   0
#define VS_OFF   4096
#define KS_OFF   8192
#define WS_OFF   10496
#define XSG_OFF  12032
#define RED_OFF  16640
#define POOL_SZ  16672

__global__ __launch_bounds__(512, 4) void qkv_attn_safe(
    const float* __restrict__ xin, const int* __restrict__ protok,
    const float* __restrict__ Wq, const float* __restrict__ bq,
    const float* __restrict__ Wk, const float* __restrict__ bk,
    const float* __restrict__ Wv, const float* __restrict__ bv,
    float* __restrict__ part0, float* __restrict__ part1,
    float* __restrict__ mh_out, float* __restrict__ mt_out, float* __restrict__ s_out)
{
  int blk = blockIdx.x;
  int bh = blk >> 3, kc = (blk >> 1) & 3, qh = blk & 1;
  int b = bh >> 3, h = bh & 7;
  int t = threadIdx.x;
  __shared__ __align__(16) float pool[POOL_SZ];
  {
    int jj = t >> 3, c8 = t & 7;
    pool[WS_OFF + t]        = Wq[jj * DM + h * 8 + c8];
    pool[WS_OFF + 512 + t]  = Wk[jj * DM + h * 8 + c8];
    pool[WS_OFF + 1024 + t] = Wv[jj * DM + h * 8 + c8];
  }
  int cc = t & 7, prow = t >> 3;
  float bqv = bq[h*8+cc], bkv = bk[h*8+cc], bvv = bv[h*8+cc];
  __syncthreads();
  float qn2max = 0.f, kn2max = 0.f;
  for (int ch = 0; ch < 12; ++ch) {
    int gr0 = (ch < 8) ? (qh*512 + ch*64) : (kc*256 + (ch-8)*64);
    {
      int i = t >> 3, c8 = (t & 7) * 8;
      const float4* p = (const float4*)&xin[((size_t)(b*LSEQ + gr0 + i))*DM + c8];
      float4 p0 = p[0], p1 = p[1];
      *(float4*)&pool[XSG_OFF + i*72 + c8]     = p0;
      *(float4*)&pool[XSG_OFF + i*72 + c8 + 4] = p1;
    }
    __syncthreads();
    float keep = (protok[b*LSEQ + gr0 + prow] != 0) ? 1.f : 0.f;
    if (ch < 8) {
      float aq = bqv, av = bvv;
      #pragma unroll
      for (int jj = 0; jj < DM; ++jj) {
        float xv = pool[XSG_OFF + prow*72 + jj];
        aq = fmaf(xv, pool[WS_OFF + jj*8 + cc], aq);
        av = fmaf(xv, pool[WS_OFF + 1024 + jj*8 + cc], av);
      }
      aq *= keep * LOG2E;
      av *= keep;
      int lq = ch*64 + prow;
      pool[QS_OFF + lq*8 + cc] = aq;
      pool[VS_OFF + lq*8 + cc] = av;
      float s2 = aq * aq;
      s2 += __shfl_xor(s2, 1); s2 += __shfl_xor(s2, 2); s2 += __shfl_xor(s2, 4);
      qn2max = fmaxf(qn2max, s2);
    } else {
      float ak = bkv;
      #pragma unroll
      for (int jj = 0; jj < DM; ++jj)
        ak = fmaf(pool[XSG_OFF + prow*72 + jj], pool[WS_OFF + 512 + jj*8 + cc], ak);
      ak *= keep;
      int lk = (ch-8)*64 + prow;
      pool[KS_OFF + lk*9 + cc] = ak;
      float k2 = ak * ak;
      k2 += __shfl_xor(k2, 1); k2 += __shfl_xor(k2, 2); k2 += __shfl_xor(k2, 4);
      kn2max = fmaxf(kn2max, k2);
    }
    __syncthreads();
  }
  int wid = t >> 6, lane = t & 63;
  {
    float qm = wmax64(qn2max), km = wmax64(kn2max);
    if (lane == 0) { pool[RED_OFF + wid] = qm; pool[RED_OFF + 16 + wid] = km; }
  }
  __syncthreads();
  float qn2 = pool[RED_OFF], kn2 = pool[RED_OFF + 16];
  #pragma unroll
  for (int i = 1; i < 8; ++i) {
    qn2 = fmaxf(qn2, pool[RED_OFF + i]);
    kn2 = fmaxf(kn2, pool[RED_OFF + 16 + i]);
  }
  float mhat = sqrtf(qn2 * kn2);
  __syncthreads();
  int j = wid, kg = lane;
  float kr[4][8], pjm[4];
  #pragma unroll
  for (int kk = 0; kk < 4; ++kk) {
    #pragma unroll
    for (int dd = 0; dd < 8; ++dd) kr[kk][dd] = pool[KS_OFF + (kk*64+kg)*9 + dd];
    pjm[kk] = ((protok[b*LSEQ + kc*256 + kk*64 + kg] != 0) ? 0.f : -1.0e9f) - mhat;
  }
  float acc[4][8] = {};
  float st = 0.f, mu_sh = -3.0e38f;
  int q0 = j * 64;
  for (int q = q0; q < q0 + 64; ++q) {
    float4 a  = *(const float4*)&pool[QS_OFF + q*8];
    float4 b4 = *(const float4*)&pool[QS_OFF + q*8 + 4];
    float4 c0 = *(const float4*)&pool[VS_OFF + q*8];
    float4 c1 = *(const float4*)&pool[VS_OFF + q*8 + 4];
    float qv[8] = {a.x,a.y,a.z,a.w,b4.x,b4.y,b4.z,b4.w};
    float vv[8] = {c0.x,c0.y,c0.z,c0.w,c1.x,c1.y,c1.z,c1.w};
    #pragma unroll
    for (int kk = 0; kk < 4; ++kk) {
      float d = pjm[kk];
      #pragma unroll
      for (int dd = 0; dd < 8; ++dd) d = fmaf(qv[dd], kr[kk][dd], d);
      mu_sh = fmaxf(mu_sh, d);
      float e = EXP2(d);
      st += e;
      #pragma unroll
      for (int dd = 0; dd < 8; ++dd) acc[kk][dd] = fmaf(e, vv[dd], acc[kk][dd]);
    }
  }
  __syncthreads();
  {
    float mw = wmax64(mu_sh), sw = wsum64(st);
    if (lane == 0) { pool[RED_OFF + wid] = mw; pool[RED_OFF + 16 + wid] = sw; }
  }
  __syncthreads();
  if (t == 0) {
    float m = pool[RED_OFF], s = pool[RED_OFF + 16];
    #pragma unroll
    for (int i = 1; i < 8; ++i) {
      m = fmaxf(m, pool[RED_OFF + i]);
      s += pool[RED_OFF + 16 + i];
    }
    s_out[blk] = s; mh_out[blk] = mhat; mt_out[blk] = m + mhat;
  }
  __syncthreads();
#define MWRITE(DW) { _Pragma("unroll") for (int kk = 0; kk < 4; ++kk) \
    { _Pragma("unroll") for (int dd = 0; dd < 8; ++dd) \
      pool[(DW)*2112 + kg*33 + kk*8 + dd] = acc[kk][dd]; } }
#define MADD(SW) { _Pragma("unroll") for (int kk = 0; kk < 4; ++kk) \
    { _Pragma("unroll") for (int dd = 0; dd < 8; ++dd) \
      acc[kk][dd] += pool[(SW)*2112 + kg*33 + kk*8 + dd]; } }
  if (j >= 4) MWRITE(j - 4);
  __syncthreads();
  if (j < 4) MADD(j);
  __syncthreads();
  if (j == 2 || j == 3) MWRITE(j - 2);
  __syncthreads();
  if (j < 2) MADD(j);
  __syncthreads();
  if (j == 1) MWRITE(0);
  __syncthreads();
  if (j == 0) {
    MADD(0);
    float* part = qh ? part1 : part0;
    #pragma unroll
    for (int kk = 0; kk < 4; ++kk) {
      float* dst = &part[((size_t)(b*LSEQ + kc*256 + kk*64 + kg))*DM + h*8];
      *(float4*)dst     = make_float4(acc[kk][0], acc[kk][1], acc[kk][2], acc[kk][3]);
      *(float4*)(dst+4) = make_float4(acc[kk][4], acc[kk][5], acc[kk][6], acc[kk][7]);
    }
  }
#undef MWRITE
#undef MADD
}

__global__ void attn_combine(const float* __restrict__ mh, const float* __restrict__ mt,
                             const float* __restrict__ sp, const float* __restrict__ nz,
                             float* __restrict__ cs){
  int bh = threadIdx.x;
  float mhl[8], sl[8];
  float mu = -3.0e38f;
  #pragma unroll
  for (int i = 0; i < 8; ++i) {
    mhl[i] = mh[bh*8+i]; sl[i] = sp[bh*8+i];
    mu = fmaxf(mu, mt[bh*8+i]);
  }
  float S = 0.f;
  #pragma unroll
  for (int i = 0; i < 8; ++i) S += sl[i] * EXP2(mhl[i] - mu);
  float w = nz[bh >> 3] / S;
  float gm = wmax64(w);
  float c = w / gm;
  #pragma unroll
  for (int i = 0; i < 8; ++i) cs[i*64 + bh] = c * EXP2(mhl[i] - mu);
}

__global__ __launch_bounds__(512) void oproj_ln(
    float* part0, const float* __restrict__ part1, const float* __restrict__ cs,
    const float* __restrict__ Wo, const float* __restrict__ bo,
    const float* __restrict__ xin, const float* __restrict__ g,
    const float* __restrict__ be, const int* __restrict__ protok)
{
  int tid = threadIdx.x, rl = tid >> 6, c = tid & 63;
  int r = blockIdx.x * 8 + rl;
  int bh = ((r >> 10) << 3) + (c >> 3);
  int kc = (r >> 8) & 3;
  __shared__ float As[8][64];
  float cs0 = cs[(kc*2)*64 + bh], cs1 = cs[(kc*2+1)*64 + bh];
  As[rl][c] = part0[(size_t)r * DM + c] * cs0 + part1[(size_t)r * DM + c] * cs1;
  __syncthreads();
  float acc = bo[c];
  #pragma unroll
  for (int jj = 0; jj < DM; ++jj) acc = fmaf(As[rl][jj], Wo[jj * DM + c], acc);
  float keep = (protok[r] != 0) ? 1.f : 0.f;
  float v = xin[(size_t)r * DM + c] + acc * keep;
  float mu = wsum64(v) * 0.015625f;
  float d = v - mu;
  float var = wsum64(d * d) * 0.015625f;
  float o = d * rsqrtf(var + 1e-9f) * g[c] + be[c];
  part0[(size_t)r * DM + c] = o * keep;
}

__global__ __launch_bounds__(512) void ffn_ln(
    const float* __restrict__ out1,
    const float* __restrict__ W1, const float* __restrict__ b1,
    const float* __restrict__ W2, const float* __restrict__ b2,
    const float* __restrict__ g, const float* __restrict__ be,
    const int* __restrict__ protok, float* __restrict__ xout)
{
  int tid = threadIdx.x, rl = tid >> 6, c = tid & 63;
  int r = blockIdx.x * 8 + rl;
  __shared__ float xs[8][64];
  __shared__ float h1s[8][DFF];
  xs[rl][c] = out1[(size_t)r * DM + c];
  __syncthreads();
  #pragma unroll
  for (int s = 0; s < 4; ++s) {
    int col = c + 64 * s;
    float a = b1[col];
    #pragma unroll
    for (int jj = 0; jj < DM; ++jj) a = fmaf(xs[rl][jj], W1[jj * DFF + col], a);
    h1s[rl][col] = fmaxf(a, 0.f);
  }
  __syncthreads();
  float a2 = b2[c];
  #pragma unroll 8
  for (int jj = 0; jj < DFF; ++jj) a2 = fmaf(h1s[rl][jj], W2[jj * DM + c], a2);
  float keep = (protok[r] != 0) ? 1.f : 0.f;
  float v = xs[rl][c] + a2 * keep;
  float mu = wsum64(v) * 0.015625f;
  float d = v - mu;
  float var = wsum64(d * d) * 0.015625f;
  float o = d * rsqrtf(var + 1e-9f) * g[c] + be[c];
  xout[(size_t)r * DM + c] = o * keep;
}

extern "C" void kernel_launch(void* const* d_in, const int* in_sizes, int n_in,
                              void* d_out, int out_size, void* d_ws, size_t ws_size,
                              hipStream_t stream) {
  const float* x      = (const float*)d_in[0];
  const int*   protok = (const int*)d_in[1];
  const float* Wq = (const float*)d_in[2];  const float* bq = (const float*)d_in[3];
  const float* Wk = (const float*)d_in[4];  const float* bk = (const float*)d_in[5];
  const float* Wv = (const float*)d_in[6];  const float* bv = (const float*)d_in[7];
  const float* Wo = (const float*)d_in[8];  const float* bo = (const float*)d_in[9];
  const float* W1 = (const float*)d_in[10]; const float* b1 = (const float*)d_in[11];
  const float* W2 = (const float*)d_in[12]; const float* b2 = (const float*)d_in[13];
  const float* g1 = (const float*)d_in[14]; const float* be1 = (const float*)d_in[15];
  const float* g2 = (const float*)d_in[16]; const float* be2 = (const float*)d_in[17];

  const size_t N = (size_t)NROW * DM;   // 524288
  const size_t fast_need = (7 * N + 4096) * sizeof(float);   // ~14.7 MB
  bool fast = (ws_size >= fast_need);

  nz_kernel<<<NB, 1024, 0, stream>>>(protok, (float*)d_ws + (fast ? 7*N : 2*N + 2048));

  if (fast) {
    float* xf   = (float*)d_ws;         // N
    float* po   = xf + N;               // N (p0)
    float* p2   = po + N;               // N
    float* p3   = p2 + N;               // N
    float* qbuf = p3 + N;               // N
    float* kbuf = qbuf + N;             // N
    float* vbuf = kbuf + N;             // N
    float* nzb  = vbuf + N;             // 8
    float* mtb  = nzb + 16;             // 1024
    float* spb  = mtb + 1024;           // 1024
    float* p1   = (float*)d_out;        // N (scratch slab; final tail overwrites)

    for (int l = 0; l < NLAYER; ++l) {
      const float* Wq_l = Wq + (size_t)l*DM*DM;  const float* bq_l = bq + (size_t)l*DM;
      const float* Wk_l = Wk + (size_t)l*DM*DM;  const float* bk_l = bk + (size_t)l*DM;
      const float* Wv_l = Wv + (size_t)l*DM*DM;  const float* bv_l = bv + (size_t)l*DM;
      const float* Wo_l = Wo + (size_t)l*DM*DM;  const float* bo_l = bo + (size_t)l*DM;
      const float* W1_l = W1 + (size_t)l*DM*DFF; const float* b1_l = b1 + (size_t)l*DFF;
      const float* W2_l = W2 + (size_t)l*DFF*DM; const float* b2_l = b2 + (size_t)l*DM;
      const float* g1_l = g1 + (size_t)l*DM;  const float* be1_l = be1 + (size_t)l*DM;
      const float* g2_l = g2 + (size_t)l*DM;  const float* be2_l = be2 + (size_t)l*DM;
      const float* xin = (l == 0) ? x : xf;
      float* xout = (l == NLAYER - 1) ? (float*)d_out : xf;

      qkv_proj<<<NROW/8, 256, 0, stream>>>(xin, protok, Wq_l, bq_l, Wk_l, bk_l,
                                           Wv_l, bv_l, qbuf, kbuf, vbuf);
      qkv_attn_fast<<<1024, 512, 0, stream>>>(qbuf, kbuf, vbuf, protok,
                                              po, p1, p2, p3, mtb, spb);
      tail_fast<<<NROW/8, 256, 0, stream>>>(po, p1, p2, p3, mtb, spb, nzb,
                                            Wo_l, bo_l, xin, g1_l, be1_l,
                                            W1_l, b1_l, W2_l, b2_l, g2_l, be2_l,
                                            protok, xout);
    }
  } else {
    float* xf   = (float*)d_ws;
    float* po   = xf + N;
    float* nzb  = po + N + 2048;
    float* mh   = nzb + 8;
    float* mt   = mh + 512;
    float* sp   = mt + 512;
    float* cs   = sp + 512;
    float* p1   = (float*)d_out;

    for (int l = 0; l < NLAYER; ++l) {
      const float* Wq_l = Wq + (size_t)l*DM*DM;  const float* bq_l = bq + (size_t)l*DM;
      const float* Wk_l = Wk + (size_t)l*DM*DM;  const float* bk_l = bk + (size_t)l*DM;
      const float* Wv_l = Wv + (size_t)l*DM*DM;  const float* bv_l = bv + (size_t)l*DM;
      const float* Wo_l = Wo + (size_t)l*DM*DM;  const float* bo_l = bo + (size_t)l*DM;
      const float* W1_l = W1 + (size_t)l*DM*DFF; const float* b1_l = b1 + (size_t)l*DFF;
      const float* W2_l = W2 + (size_t)l*DFF*DM; const float* b2_l = b2 + (size_t)l*DM;
      const float* g1_l = g1 + (size_t)l*DM;  const float* be1_l = be1 + (size_t)l*DM;
      const float* g2_l = g2 + (size_t)l*DM;  const float* be2_l = be2 + (size_t)l*DM;
      const float* xin = (l == 0) ? x : xf;
      float* xout = (l == NLAYER - 1) ? (float*)d_out : xf;

      qkv_attn_safe<<<512, 512, 0, stream>>>(xin, protok, Wq_l, bq_l, Wk_l, bk_l,
                                             Wv_l, bv_l, po, p1, mh, mt, sp);
      attn_combine<<<1, 64, 0, stream>>>(mh, mt, sp, nzb, cs);
      oproj_ln<<<NROW/8, 512, 0, stream>>>(po, p1, cs, Wo_l, bo_l, xin, g1_l, be1_l, protok);
      ffn_ln<<<NROW/8, 512, 0, stream>>>(po, W1_l, b1_l, W2_l, b2_l, g2_l, be2_l, protok, xout);
    }
  }
}